// Round 1
// 238.693 us; speedup vs baseline: 1.0013x; 1.0013x over previous
//
#include <hip/hip_runtime.h>
#include <hip/hip_bf16.h>

#define P_CLS 512
#define D_DIM 2048
#define CAP   32
#define TAU_INV 2.0f

typedef short short8 __attribute__((ext_vector_type(8)));
typedef float f32x4 __attribute__((ext_vector_type(4)));

__device__ __forceinline__ unsigned short f2bf_bits(float x) {
  __hip_bfloat16 b = __float2bfloat16(x);
  unsigned short u;
  __builtin_memcpy(&u, &b, sizeof(u));
  return u;
}

__device__ __forceinline__ float xred_sum(float v) {
#pragma unroll
  for (int o = 1; o < 64; o <<= 1) v += __shfl_xor(v, o, 64);
  return v;
}
__device__ __forceinline__ float xred_max(float v) {
#pragma unroll
  for (int o = 1; o < 64; o <<= 1) v = fmaxf(v, __shfl_xor(v, o, 64));
  return v;
}

__global__ void k_init(int* cnt, float* accs) {
  int t = blockIdx.x * blockDim.x + threadIdx.x;
  if (t < P_CLS) cnt[t] = 0;
  if (t < 8) accs[t] = 0.f;
}

__global__ void k_index(const int* __restrict__ label, int* __restrict__ cnt,
                        int* __restrict__ idx, int n) {
  int i = blockIdx.x * blockDim.x + threadIdx.x;
  if (i < n) {
    int p = label[i];
    int slot = atomicAdd(&cnt[p], 1);
    if (slot < CAP) idx[p * CAP + slot] = i;
  }
}

// Block of 256 per (class p, modality m). Wave-per-row register pipeline:
// lane l holds 32 floats of a row (f32x4 at vector index lane+64j), so the
// row norm is lane-local ssq + shfl_xor reduce -- NO block barrier in the
// main loop. Two register row-buffers ping-pong so each wave always has the
// next row's 8 KB of global loads in flight (latency hiding by ILP+TLP,
// not barrier-phased LDS staging). Epilogue merges the 4 wave accumulators
// through 32 KB LDS.
__global__ __launch_bounds__(256)
void k_centers(const float* __restrict__ f0, const float* __restrict__ f1,
               const float* __restrict__ f2, const int* __restrict__ cnt,
               const int* __restrict__ idx, __hip_bfloat16* __restrict__ cb,
               float* __restrict__ accs) {
  __shared__ __align__(16) f32x4 red[4][D_DIM / 4];  // 32 KiB
  __shared__ float scr[4];
  int p = blockIdx.x, m = blockIdx.y;
  const float* F = (m == 0) ? f0 : (m == 1) ? f1 : f2;
  int t = threadIdx.x, lane = t & 63, wv = t >> 6;
  int c = cnt[p];
  if (c > CAP) c = CAP;
  const int* idxp = idx + p * CAP;

  // wave wv handles rows wv, wv+4, wv+8, ...
  int nr = (c > wv) ? ((c - wv + 3) >> 2) : 0;

  f32x4 acc[8] = {{0,0,0,0},{0,0,0,0},{0,0,0,0},{0,0,0,0},
                  {0,0,0,0},{0,0,0,0},{0,0,0,0},{0,0,0,0}};
  f32x4 a[8], b[8];

  auto loadrow = [&](f32x4* buf, int r) {
    const f32x4* rp = (const f32x4*)(F + (long)idxp[r] * D_DIM);
#pragma unroll
    for (int j = 0; j < 8; ++j) buf[j] = rp[lane + 64 * j];
  };
  auto consume = [&](const f32x4* buf) {
    float ssq = 0.f;
#pragma unroll
    for (int j = 0; j < 8; ++j) {
      f32x4 q = buf[j] * buf[j];
      ssq += q.x + q.y + q.z + q.w;
    }
    ssq = xred_sum(ssq);
    float w = 1.0f / fmaxf(sqrtf(ssq), 1e-12f);
#pragma unroll
    for (int j = 0; j < 8; ++j) acc[j] += buf[j] * w;
  };

  if (nr > 0) loadrow(a, wv);
  if (nr > 1) loadrow(b, wv + 4);
  for (int k = 0; k < nr; k += 2) {
    consume(a);
    if (k + 2 < nr) loadrow(a, wv + 4 * (k + 2));
    if (k + 1 < nr) {
      consume(b);
      if (k + 3 < nr) loadrow(b, wv + 4 * (k + 3));
    }
  }

  // merge the 4 wave accumulators; acc[j] is the row f32x4 at vector index
  // lane + 64*j, so red[wv] laid out by that index is the row in natural order.
#pragma unroll
  for (int j = 0; j < 8; ++j) red[wv][lane + 64 * j] = acc[j];
  __syncthreads();
  f32x4 s0 = red[0][t] + red[1][t] + red[2][t] + red[3][t];
  f32x4 s1 = red[0][t + 256] + red[1][t + 256] + red[2][t + 256] + red[3][t + 256];
  f32x4 q0 = s0 * s0, q1 = s1 * s1;
  float s2 = q0.x + q0.y + q0.z + q0.w + q1.x + q1.y + q1.z + q1.w;
  s2 = xred_sum(s2);
  if (lane == 0) scr[wv] = s2;
  __syncthreads();
  s2 = scr[0] + scr[1] + scr[2] + scr[3];
  float sn = sqrtf(s2);
  float inv = 1.0f / fmaxf(sn, 1e-12f);
  __hip_bfloat16* dst = cb + ((long)m * P_CLS + p) * D_DIM;
  f32x4 o0 = s0 * inv, o1 = s1 * inv;
  ushort4 h0, h1;
  h0.x = f2bf_bits(o0.x); h0.y = f2bf_bits(o0.y);
  h0.z = f2bf_bits(o0.z); h0.w = f2bf_bits(o0.w);
  h1.x = f2bf_bits(o1.x); h1.y = f2bf_bits(o1.y);
  h1.z = f2bf_bits(o1.z); h1.w = f2bf_bits(o1.w);
  ((ushort4*)dst)[t] = h0;
  ((ushort4*)dst)[t + 256] = h1;
  if (t == 0 && c > 0) atomicAdd(&accs[0], sn);
}

// Split-K bf16 MFMA GEMM (gridDim.z slices), 64x64 tiles, LDS double-buffer
// + depth-2 reg prefetch, one barrier per K-step.
__global__ __launch_bounds__(256)
void k_gemm(const __hip_bfloat16* __restrict__ cbh, float* __restrict__ logits) {
  __shared__ __align__(16) unsigned short As[2][64 * 40], Bs[2][64 * 40];
  int pair = blockIdx.y, kz = blockIdx.z, nkz = gridDim.z;
  int ksl = D_DIM / nkz;
  int ma = (pair == 2) ? 1 : 0;
  int mb = (pair == 0) ? 1 : 2;
  const unsigned short* A =
      (const unsigned short*)cbh + (long)ma * P_CLS * D_DIM + kz * ksl;
  const unsigned short* B =
      (const unsigned short*)cbh + (long)mb * P_CLS * D_DIM + kz * ksl;
  float* C = logits + ((long)kz * 3 + pair) * P_CLS * P_CLS;
  int tm = (blockIdx.x >> 3) * 64, tn = (blockIdx.x & 7) * 64;
  int t = threadIdx.x, lane = t & 63, wv = t >> 6;
  int srow = t >> 2, skc = (t & 3) * 8;
  int quad = lane >> 4, mr = lane & 15;
  const unsigned short* pa = A + (long)(tm + srow) * D_DIM + skc;
  const unsigned short* pb = B + (long)(tn + srow) * D_DIM + skc;
  f32x4 acc[4] = {{0,0,0,0},{0,0,0,0},{0,0,0,0},{0,0,0,0}};
  uint4 av = *(const uint4*)pa, bv = *(const uint4*)pb;
  *(uint4*)(&As[0][srow * 40 + skc]) = av;
  *(uint4*)(&Bs[0][srow * 40 + skc]) = bv;
  av = *(const uint4*)(pa + 32); bv = *(const uint4*)(pb + 32);
  const int NIT = ksl / 32;
  for (int it = 0; it < NIT; ++it) {
    __syncthreads();
    int cur = it & 1;
    if (it + 1 < NIT) {
      *(uint4*)(&As[cur ^ 1][srow * 40 + skc]) = av;
      *(uint4*)(&Bs[cur ^ 1][srow * 40 + skc]) = bv;
    }
    if (it + 2 < NIT) {
      av = *(const uint4*)(pa + (it + 2) * 32);
      bv = *(const uint4*)(pb + (it + 2) * 32);
    }
    short8 af = *(const short8*)(&As[cur][(wv * 16 + mr) * 40 + quad * 8]);
#pragma unroll
    for (int nb = 0; nb < 4; ++nb) {
      short8 bfr = *(const short8*)(&Bs[cur][(nb * 16 + mr) * 40 + quad * 8]);
      acc[nb] = __builtin_amdgcn_mfma_f32_16x16x32_bf16(af, bfr, acc[nb], 0, 0, 0);
    }
  }
  int crow = tm + wv * 16 + quad * 4;
#pragma unroll
  for (int nb = 0; nb < 4; ++nb)
#pragma unroll
    for (int r = 0; r < 4; ++r)
      C[(long)(crow + r) * P_CLS + tn + nb * 16 + mr] = acc[nb][r] * TAU_INV;
}

// One block per (pair,p) row: sum nkz split-K partials, logsumexp - diag.
__global__ __launch_bounds__(256)
void k_lse(const float* __restrict__ logits, float* __restrict__ accs, int nkz) {
  __shared__ float sred[8];
  int row = blockIdx.x;  // 0 .. 3*P-1
  int p = row & (P_CLS - 1);
  int t = threadIdx.x, lane = t & 63, wv = t >> 6;
  float v0 = 0.f, v1 = 0.f, diag = 0.f;
  for (int z = 0; z < nkz; ++z) {
    const float* L = logits + ((long)z * 3 * P_CLS + row) * P_CLS;
    v0 += L[t];
    v1 += L[t + 256];
  }
  float mx = xred_max(fmaxf(v0, v1));
  if (lane == 0) sred[wv] = mx;
  __syncthreads();
  mx = fmaxf(fmaxf(sred[0], sred[1]), fmaxf(sred[2], sred[3]));
  float e = expf(v0 - mx) + expf(v1 - mx);
  e = xred_sum(e);
  if (lane == 0) sred[4 + wv] = e;
  __syncthreads();
  if (t == 0) {
    float tot = sred[4] + sred[5] + sred[6] + sred[7];
    for (int z = 0; z < nkz; ++z)
      diag += logits[((long)z * 3 * P_CLS + row) * P_CLS + p];
    atomicAdd(&accs[1], mx + logf(tot) - diag);
  }
}

__global__ void k_final(const float* __restrict__ accs, float* __restrict__ out,
                        float invN) {
  out[0] = 6.0f - 2.0f * invN * accs[0] + accs[1] * (1.0f / (float)P_CLS);
}

extern "C" void kernel_launch(void* const* d_in, const int* in_sizes, int n_in,
                              void* d_out, int out_size, void* d_ws, size_t ws_size,
                              hipStream_t stream) {
  const float* fvp = (const float*)d_in[0];
  const float* fap = (const float*)d_in[1];
  const float* frp = (const float*)d_in[2];
  const int* label = (const int*)d_in[3];
  int N = in_sizes[3];

  char* ws = (char*)d_ws;
  int* cnt = (int*)ws;                                    // 2 KiB
  int* idx = (int*)(ws + 2048);                           // 64 KiB
  float* accs = (float*)(ws + 2048 + 65536);              // 32 B
  __hip_bfloat16* cb = (__hip_bfloat16*)(ws + 131072);    // 6 MiB
  float* logits = (float*)(ws + 131072 + 3ul * P_CLS * D_DIM * 2);

  size_t base = 131072 + 3ul * P_CLS * D_DIM * 2;
  size_t per_z = 3ul * P_CLS * P_CLS * 4;
  int KZ = (ws_size >= base + 4 * per_z) ? 4 : 2;

  hipLaunchKernelGGL(k_init, dim3(1), dim3(512), 0, stream, cnt, accs);
  hipLaunchKernelGGL(k_index, dim3((N + 255) / 256), dim3(256), 0, stream,
                     label, cnt, idx, N);
  hipLaunchKernelGGL(k_centers, dim3(P_CLS, 3), dim3(256), 0, stream,
                     fvp, fap, frp, cnt, idx, cb, accs);
  hipLaunchKernelGGL(k_gemm, dim3(64, 3, KZ), dim3(256), 0, stream, cb, logits);
  hipLaunchKernelGGL(k_lse, dim3(3 * P_CLS), dim3(256), 0, stream, logits, accs, KZ);
  hipLaunchKernelGGL(k_final, dim3(1), dim3(1), 0, stream, accs, (float*)d_out,
                     1.0f / (float)N);
}